// Round 7
// baseline (79.528 us; speedup 1.0000x reference)
//
#include <hip/hip_runtime.h>
#include <math.h>

// LDE via MFMA, two kernels (R7).
// dis^2 = ||x||^2 - 2*(x.dic) + ||dic||^2; GEMM1 (x.dicT, bf16 hi+lo A vs
// bf16 dic) and GEMM2 (e^T.x_hi) on mfma_f32_16x16x32_bf16.
// R7 vs R6: Tc 64->32 (grid 512->1024; lde_main was 2 blocks/CU = 25%
// occupancy, latency-bound). One GEMM1 tile per wave (ts=w>>1, nt=w&1).
// Records' A-part stored bf16 so total record bytes stay ~8.7 MB at NCH=64.

constexpr int Bn = 8, Tn = 2048, Dn = 64, Fn = 128;
constexpr int Tc = 32, DG = 32;
constexpr int NCH = Tn / Tc;        // 64 chunks per (b,dg)
constexpr int NDG = Dn / DG;        // 2
constexpr int XT = 40;              // xsT row stride (ushorts); 80B, 16B-aligned
constexpr int ESS = 40;             // es row stride
constexpr int DS = 136;             // dic_hi row stride
constexpr int RECA = DG * Fn;               // 4096 bf16 A values
constexpr size_t RECB = (size_t)RECA * 2 + 2 * DG * 4;   // 8448 B/record (16B-mult)

typedef short short8 __attribute__((ext_vector_type(8)));
typedef float f32x4 __attribute__((ext_vector_type(4)));

__device__ inline unsigned short f2bf(float v) {          // RNE float->bf16
    union { float f; unsigned u; } c; c.f = v;
    return (unsigned short)((c.u + 0x7FFF + ((c.u >> 16) & 1)) >> 16);
}
__device__ inline float bf2f(unsigned short h) {
    union { unsigned u; float f; } c; c.u = ((unsigned)h) << 16;
    return c.f;
}

__global__ __launch_bounds__(256, 4) void lde_main(
    const float* __restrict__ x, const float* __restrict__ dic,
    const float* __restrict__ wei, char* __restrict__ ws)
{
    const int b  = blockIdx.x & 7;                 // low bits -> XCD affinity for x[b]
    const int dg = (blockIdx.x >> 3) & (NDG - 1);
    const int tc = blockIdx.x >> 4;
    const int t0 = tc * Tc;
    const int d0 = dg * DG;

    __shared__ unsigned short xsT[Fn * XT];        // x bf16 hi, [f][t]   10.0 KB
    __shared__ unsigned short es[DG * ESS];        // e bf16, [d][t]       2.5 KB
    __shared__ unsigned short dic_hi[DG * DS];     // dic bf16, [d][f]     8.5 KB
    __shared__ float sq[Tc], sp[DG];
    __shared__ float wstat[2][DG], wsum[2][DG];

    const int tid  = threadIdx.x;
    const int w    = tid >> 6;                     // wave 0..3
    const int lane = tid & 63;
    const int l15  = lane & 15;
    const int quad = lane >> 4;
    const int ts   = w >> 1;                       // t-slab 0..1
    const int nt   = w & 1;                        // d-tile 0..1
    const int tA   = ts * 16 + l15;                // this lane's GEMM1 A row (local t)

    // ---- x: row loads -> register A-frags (hi+lo); nt==0 waves scatter xsT+sq ----
    short8 ahi[4], alo[4];
    {
        const float* xr = x + ((size_t)b * Tn + t0 + tA) * Fn + quad * 8;
        float q = 0.f;
        #pragma unroll
        for (int k = 0; k < 4; ++k) {              // f = k*32 + quad*8 + j
            float4 v0 = *(const float4*)(xr + k * 32);
            float4 v1 = *(const float4*)(xr + k * 32 + 4);
            float vv[8] = {v0.x, v0.y, v0.z, v0.w, v1.x, v1.y, v1.z, v1.w};
            #pragma unroll
            for (int j = 0; j < 8; ++j) {
                unsigned short h = f2bf(vv[j]);
                ahi[k][j] = (short)h;
                alo[k][j] = (short)f2bf(vv[j] - bf2f(h));
                q += vv[j] * vv[j];
                if (nt == 0)
                    xsT[(k * 32 + quad * 8 + j) * XT + tA] = h;  // transpose scatter
            }
        }
        q += __shfl_xor(q, 16);                    // sum the 4 quads of row tA
        q += __shfl_xor(q, 32);
        if (nt == 0 && quad == 0) sq[tA] = q;      // exact fp32 ||x_t||^2
    }

    // ---- dic -> bf16 LDS (hi only); sp[d] = ||dic_d||^2 exact ----
    {
        int dl = tid >> 3, fq = (tid & 7) * 16;    // 8 threads per d, 16 f each
        const float4* dp = (const float4*)(dic + (size_t)(d0 + dl) * Fn + fq);
        float p = 0.f;
        #pragma unroll
        for (int i = 0; i < 4; ++i) {
            float4 v = dp[i];
            p += v.x * v.x + v.y * v.y + v.z * v.z + v.w * v.w;
            *(ushort4*)&dic_hi[dl * DS + fq + i * 4] =
                make_ushort4(f2bf(v.x), f2bf(v.y), f2bf(v.z), f2bf(v.w));
        }
        #pragma unroll
        for (int m = 4; m >= 1; m >>= 1) p += __shfl_xor(p, m);
        if ((tid & 7) == 0) sp[dl] = p;
    }

    // ---- logsumexp(wei), redundantly per wave ----
    float lse;
    {
        float wv = wei[lane];                      // D=64 = wave width
        float m = wv;
        #pragma unroll
        for (int k = 32; k >= 1; k >>= 1) m = fmaxf(m, __shfl_xor(m, k));
        float e = expf(wv - m), s = e;
        #pragma unroll
        for (int k = 32; k >= 1; k >>= 1) s += __shfl_xor(s, k);
        lse = m + logf(s);
    }
    __syncthreads();                               // xsT, dic_hi, sq, sp ready

    // ---- GEMM1: one 16x16 tile per wave: t-slab ts x d-tile nt, K=128 ----
    f32x4 acc1 = {0.f, 0.f, 0.f, 0.f};
    #pragma unroll
    for (int k = 0; k < 4; ++k) {
        short8 bhi = *(const short8*)&dic_hi[(nt * 16 + l15) * DS + k * 32 + quad * 8];
        acc1 = __builtin_amdgcn_mfma_f32_16x16x32_bf16(ahi[k], bhi, acc1, 0, 0, 0);
        acc1 = __builtin_amdgcn_mfma_f32_16x16x32_bf16(alo[k], bhi, acc1, 0, 0, 0);
    }

    // ---- logits + chunk softmax (C layout: col=l15 -> d, row=quad*4+r -> t) ----
    const int dd = nt * 16 + l15;
    const float lsm = wei[d0 + dd] - lse;
    float logit[4], eloc[4];
    #pragma unroll
    for (int r = 0; r < 4; ++r) {
        int tt = ts * 16 + quad * 4 + r;
        float s2 = sq[tt] - 2.f * acc1[r] + sp[dd];
        logit[r] = -sqrtf(fmaxf(s2, 0.f)) * lsm;
    }
    {
        float m = fmaxf(fmaxf(logit[0], logit[1]), fmaxf(logit[2], logit[3]));
        m = fmaxf(m, __shfl_xor(m, 16));
        m = fmaxf(m, __shfl_xor(m, 32));           // slab max, replicated
        if (quad == 0) wstat[ts][dd] = m;
    }
    __syncthreads();
    const float Mc = fmaxf(wstat[0][dd], wstat[1][dd]);
    {
        float s = 0.f;
        #pragma unroll
        for (int r = 0; r < 4; ++r) {
            float e = expf(logit[r] - Mc);
            eloc[r] = e;
            s += e;
        }
        s += __shfl_xor(s, 16);
        s += __shfl_xor(s, 32);
        if (quad == 0) wsum[ts][dd] = s;
        #pragma unroll
        for (int r = 0; r < 4; ++r)                // es[d][t] bf16 (GEMM2 A layout)
            es[dd * ESS + ts * 16 + quad * 4 + r] = f2bf(eloc[r]);
    }
    __syncthreads();

    char* recb = ws + (size_t)((b * NDG + dg) * NCH + tc) * RECB;
    unsigned short* recA = (unsigned short*)recb;
    float* recMS = (float*)(recb + (size_t)RECA * 2);
    if (ts == 0 && quad == 0) {                    // chunk stats (16 lanes x 2 waves)
        recMS[dd]      = Mc;
        recMS[DG + dd] = wsum[0][dd] + wsum[1][dd];
    }

    // ---- GEMM2: A[d][f] = e^T . x_hi, K=Tc=32 (single step); wave w: f in [w*32,+32) ----
    f32x4 acc2[2][2] = {{{0.f,0.f,0.f,0.f},{0.f,0.f,0.f,0.f}},
                        {{0.f,0.f,0.f,0.f},{0.f,0.f,0.f,0.f}}};
    short8 af[2];
    #pragma unroll
    for (int mt = 0; mt < 2; ++mt)
        af[mt] = *(const short8*)&es[(mt * 16 + l15) * ESS + quad * 8];
    #pragma unroll
    for (int n2 = 0; n2 < 2; ++n2) {
        short8 bfr = *(const short8*)&xsT[(w * 32 + n2 * 16 + l15) * XT + quad * 8];
        #pragma unroll
        for (int mt = 0; mt < 2; ++mt)
            acc2[mt][n2] = __builtin_amdgcn_mfma_f32_16x16x32_bf16(af[mt], bfr, acc2[mt][n2], 0, 0, 0);
    }
    #pragma unroll
    for (int mt = 0; mt < 2; ++mt)
        #pragma unroll
        for (int n2 = 0; n2 < 2; ++n2)
            #pragma unroll
            for (int r = 0; r < 4; ++r)
                recA[(mt * 16 + quad * 4 + r) * Fn + w * 32 + n2 * 16 + l15] =
                    f2bf(acc2[mt][n2][r]);
}

__global__ __launch_bounds__(256) void lde_combine(
    const char* __restrict__ ws, const float* __restrict__ dic,
    float* __restrict__ out)
{
    const int b = blockIdx.x & 7;
    const int d = blockIdx.x >> 3;
    const int dg = d >> 5, dl = d & 31;
    const int tid = threadIdx.x;

    __shared__ float s_sc[NCH];                    // exp(Mc - M) per chunk
    __shared__ float s_S;
    __shared__ float s_pa[Fn];

    const char* base = ws + (size_t)((b * NDG + dg) * NCH) * RECB;

    // ---- M and S across 64 chunks, one lane per chunk ----
    if (tid < 64) {
        const float* ms = (const float*)(base + (size_t)tid * RECB + (size_t)RECA * 2);
        float Mc = ms[dl];
        float Sc = ms[DG + dl];
        float M = Mc;
        #pragma unroll
        for (int m = 32; m >= 1; m >>= 1) M = fmaxf(M, __shfl_xor(M, m));
        float sck = expf(Mc - M);
        float S = Sc * sck;                        // Sc multiplies ONLY the S-sum
        #pragma unroll
        for (int m = 32; m >= 1; m >>= 1) S += __shfl_xor(S, m);
        s_sc[tid] = sck;
        if (tid == 0) s_S = S;
    }
    __syncthreads();

    // ---- A-merge: 256 threads = 128 f x 2 chunk-halves ----
    const int f = tid & 127, h = tid >> 7;
    float a = 0.f;
    #pragma unroll 4
    for (int i = 0; i < NCH / 2; ++i) {
        int c = h * (NCH / 2) + i;
        const unsigned short* rA = (const unsigned short*)(base + (size_t)c * RECB);
        a += bf2f(rA[dl * Fn + f]) * s_sc[c];
    }
    if (h == 1) s_pa[f] = a;
    __syncthreads();
    if (h == 0) {
        a += s_pa[f];
        float S = s_S;
        out[((size_t)b * Dn + d) * Fn + f] = (a - S * dic[d * Fn + f]) / S;
    }
}

extern "C" void kernel_launch(void* const* d_in, const int* in_sizes, int n_in,
                              void* d_out, int out_size, void* d_ws, size_t ws_size,
                              hipStream_t stream) {
    const float* x   = (const float*)d_in[0];
    const float* dic = (const float*)d_in[1];
    const float* wei = (const float*)d_in[2];
    float* out = (float*)d_out;
    char* ws   = (char*)d_ws;                      // records: 16*64*8448 B = 8.65 MB

    hipLaunchKernelGGL(lde_main, dim3(Bn * NDG * NCH), dim3(256), 0, stream,
                       x, dic, wei, ws);
    hipLaunchKernelGGL(lde_combine, dim3(Bn * Dn), dim3(256), 0, stream,
                       ws, dic, out);
}